// Round 1
// baseline (281.484 us; speedup 1.0000x reference)
//
#include <hip/hip_runtime.h>
#include <hip/hip_bf16.h>

#define B_SZ 8192
#define S_DIM 512
#define H_DIM 1024
#define E_DIM 256
#define A_DIM 32

typedef __attribute__((ext_vector_type(4))) float f32x4;
typedef __attribute__((ext_vector_type(8))) __bf16 bf16x8;

using as1_void = __attribute__((address_space(1))) void;
using as3_void = __attribute__((address_space(3))) void;

__device__ __forceinline__ unsigned short f2bfu(float f) {
  unsigned u = __builtin_bit_cast(unsigned, f);
  unsigned r = (u + 0x7FFFu + ((u >> 16) & 1u)) >> 16;
  return (unsigned short)r;
}
__device__ __forceinline__ float bf2f(unsigned short x) {
  unsigned u = ((unsigned)x) << 16;
  return __builtin_bit_cast(float, u);
}

// elementwise f32 -> bf16 (n multiple of 4)
__global__ void conv_kernel(const float* __restrict__ in, unsigned short* __restrict__ out, int n) {
  int i = blockIdx.x * blockDim.x + threadIdx.x;
  int idx = i * 4;
  if (idx >= n) return;
  const float4 v = *(const float4*)(in + idx);
  ushort4 o;
  o.x = f2bfu(v.x); o.y = f2bfu(v.y); o.z = f2bfu(v.z); o.w = f2bfu(v.w);
  *(ushort4*)(out + idx) = o;
}

// transpose+convert: in [R][C] f32 -> out [C][R] bf16. R,C multiples of 32.
__global__ void tconv_kernel(const float* __restrict__ in, unsigned short* __restrict__ out,
                             int R, int C) {
  __shared__ float t[32][33];
  int tx = threadIdx.x, ty = threadIdx.y;
  int c0 = blockIdx.x * 32, r0 = blockIdx.y * 32;
#pragma unroll
  for (int i = 0; i < 4; ++i) {
    int r = r0 + ty + i * 8;
    t[ty + i * 8][tx] = in[(size_t)r * C + c0 + tx];
  }
  __syncthreads();
#pragma unroll
  for (int i = 0; i < 4; ++i) {
    int c = c0 + ty + i * 8;
    out[(size_t)c * R + r0 + tx] = f2bfu(t[tx][ty + i * 8]);
  }
}

// C[M,N] = act(A[M,K] @ B[K,N] + bias), with B given transposed: BT[N][K].
// A,BT bf16 row-major; bias f32. ACT: 0 none->f32, 1 relu->bf16, 2 abs->bf16.
// M%128==0, N%128==0, K%64==0.
template <int ACT>
__global__ void gemm_bt(const unsigned short* __restrict__ A,
                        const unsigned short* __restrict__ BT,
                        const float* __restrict__ bias, void* __restrict__ Cp,
                        int M, int N, int K) {
  __shared__ unsigned short As[128 * 64];
  __shared__ unsigned short Bs[128 * 64];
  const int tid = threadIdx.x;
  const int w = tid >> 6, l = tid & 63;
  const int wr = w >> 1, wc = w & 1;
  const int row0 = blockIdx.y * 128, col0 = blockIdx.x * 128;
  f32x4 acc[4][4] = {};
  for (int k0 = 0; k0 < K; k0 += 64) {
    __syncthreads();
#pragma unroll
    for (int i = 0; i < 4; ++i) {
      int cbase = i * 256 + w * 64;          // wave-uniform chunk base
      int c = cbase + l;                     // per-lane chunk id
      int r = c >> 3, kc = c & 7;            // A tile [128 rows][64 k], 16B chunks
      const unsigned short* src = A + (size_t)(row0 + r) * K + (k0 + kc * 8);
      __builtin_amdgcn_global_load_lds((const as1_void*)src, (as3_void*)&As[cbase * 8], 16, 0, 0);
    }
#pragma unroll
    for (int i = 0; i < 4; ++i) {
      int cbase = i * 256 + w * 64;
      int c = cbase + l;
      int r = c >> 3, kc = c & 7;            // B^T tile [128 n-rows][64 k]
      const unsigned short* src = BT + (size_t)(col0 + r) * K + (k0 + kc * 8);
      __builtin_amdgcn_global_load_lds((const as1_void*)src, (as3_void*)&Bs[cbase * 8], 16, 0, 0);
    }
    __syncthreads();
#pragma unroll
    for (int kk = 0; kk < 2; ++kk) {
      bf16x8 af[4], bfr[4];
#pragma unroll
      for (int i = 0; i < 4; ++i)
        af[i] = *(const bf16x8*)&As[(wr * 64 + i * 16 + (l & 15)) * 64 + kk * 32 + (l >> 4) * 8];
#pragma unroll
      for (int j = 0; j < 4; ++j)
        bfr[j] = *(const bf16x8*)&Bs[(wc * 64 + j * 16 + (l & 15)) * 64 + kk * 32 + (l >> 4) * 8];
#pragma unroll
      for (int i = 0; i < 4; ++i)
#pragma unroll
        for (int j = 0; j < 4; ++j)
          acc[i][j] = __builtin_amdgcn_mfma_f32_16x16x32_bf16(af[i], bfr[j], acc[i][j], 0, 0, 0);
    }
  }
#pragma unroll
  for (int i = 0; i < 4; ++i)
#pragma unroll
    for (int j = 0; j < 4; ++j)
#pragma unroll
      for (int t = 0; t < 4; ++t) {
        int r = row0 + wr * 64 + i * 16 + (l >> 4) * 4 + t;
        int c = col0 + wc * 64 + j * 16 + (l & 15);
        float v = acc[i][j][t] + bias[c];
        if (ACT == 1) v = fmaxf(v, 0.0f);
        if (ACT == 2) v = fabsf(v);
        if (ACT == 0)
          ((float*)Cp)[(size_t)r * N + c] = v;
        else
          ((unsigned short*)Cp)[(size_t)r * N + c] = f2bfu(v);
      }
}

// Per-row fusion: hidden = elu(sum_a q[a]*|w1[b,a,:]| + b1), q_tot = hidden.wf + vh.vw2 + vb2
__global__ void final_kernel(const float* __restrict__ qs, const unsigned short* __restrict__ w1c,
                             const float* __restrict__ b1, const unsigned short* __restrict__ wf,
                             const unsigned short* __restrict__ vh, const float* __restrict__ vw2,
                             const float* __restrict__ vb2, float* __restrict__ out, int row0) {
  const int tid = threadIdx.x;               // e in [0,256)
  const int b = row0 + blockIdx.x;
  const unsigned short* wrow = w1c + (size_t)blockIdx.x * (A_DIM * E_DIM);
  const float* qrow = qs + (size_t)b * A_DIM;
  float acc = b1[(size_t)b * E_DIM + tid];
#pragma unroll 8
  for (int a = 0; a < A_DIM; ++a)
    acc = fmaf(qrow[a], bf2f(wrow[a * E_DIM + tid]), acc);
  float hidden = acc > 0.0f ? acc : (expf(acc) - 1.0f);  // elu, alpha=1
  float s = hidden * bf2f(wf[(size_t)b * E_DIM + tid]) +
            bf2f(vh[(size_t)b * E_DIM + tid]) * vw2[tid];
  __shared__ float red[4];
#pragma unroll
  for (int o = 32; o > 0; o >>= 1) s += __shfl_down(s, o, 64);
  if ((tid & 63) == 0) red[tid >> 6] = s;
  __syncthreads();
  if (tid == 0) out[b] = red[0] + red[1] + red[2] + red[3] + vb2[0];
}

extern "C" void kernel_launch(void* const* d_in, const int* in_sizes, int n_in,
                              void* d_out, int out_size, void* d_ws, size_t ws_size,
                              hipStream_t stream) {
  const float* agent_qs = (const float*)d_in[0];
  const float* states = (const float*)d_in[1];
  const float* hw1_w1 = (const float*)d_in[2];
  const float* hw1_b1 = (const float*)d_in[3];
  const float* hw1_w2 = (const float*)d_in[4];
  const float* hw1_b2 = (const float*)d_in[5];
  const float* hb1_w = (const float*)d_in[6];
  const float* hb1_b = (const float*)d_in[7];
  const float* hwf_w1 = (const float*)d_in[8];
  const float* hwf_b1 = (const float*)d_in[9];
  const float* hwf_w2 = (const float*)d_in[10];
  const float* hwf_b2 = (const float*)d_in[11];
  const float* v_w1 = (const float*)d_in[12];
  const float* v_b1 = (const float*)d_in[13];
  const float* v_w2 = (const float*)d_in[14];
  const float* v_b2 = (const float*)d_in[15];
  float* out = (float*)d_out;

  size_t off = 0;
  char* ws = (char*)d_ws;
  auto carve = [&](size_t bytes) -> void* {
    void* p = ws + off;
    off = (off + bytes + 255) & ~(size_t)255;
    return p;
  };
  unsigned short* st_bf = (unsigned short*)carve((size_t)B_SZ * S_DIM * 2);
  unsigned short* w11T = (unsigned short*)carve((size_t)H_DIM * S_DIM * 2);
  unsigned short* w12T = (unsigned short*)carve((size_t)8192 * H_DIM * 2);
  unsigned short* wb1T = (unsigned short*)carve((size_t)E_DIM * S_DIM * 2);
  unsigned short* wf1T = (unsigned short*)carve((size_t)H_DIM * S_DIM * 2);
  unsigned short* wf2T = (unsigned short*)carve((size_t)E_DIM * H_DIM * 2);
  unsigned short* wv1T = (unsigned short*)carve((size_t)E_DIM * S_DIM * 2);
  unsigned short* h1 = (unsigned short*)carve((size_t)B_SZ * H_DIM * 2);
  unsigned short* hfb = (unsigned short*)carve((size_t)B_SZ * H_DIM * 2);
  float* b1f = (float*)carve((size_t)B_SZ * E_DIM * 4);
  unsigned short* wfb = (unsigned short*)carve((size_t)B_SZ * E_DIM * 2);
  unsigned short* vhb = (unsigned short*)carve((size_t)B_SZ * E_DIM * 2);
  size_t rem = (ws_size > off) ? ws_size - off : 0;
  int chunk = (int)(rem / ((size_t)8192 * 2));
  chunk &= ~127;
  if (chunk < 128) chunk = 128;
  if (chunk > B_SZ) chunk = B_SZ;
  unsigned short* w1c = (unsigned short*)(ws + off);

  // dtype converts (+ weight transposes to B^T layout)
  conv_kernel<<<(B_SZ * S_DIM / 4 + 255) / 256, 256, 0, stream>>>(states, st_bf, B_SZ * S_DIM);
  dim3 tb(32, 8);
  tconv_kernel<<<dim3(H_DIM / 32, S_DIM / 32), tb, 0, stream>>>(hw1_w1, w11T, S_DIM, H_DIM);
  tconv_kernel<<<dim3(8192 / 32, H_DIM / 32), tb, 0, stream>>>(hw1_w2, w12T, H_DIM, 8192);
  tconv_kernel<<<dim3(E_DIM / 32, S_DIM / 32), tb, 0, stream>>>(hb1_w, wb1T, S_DIM, E_DIM);
  tconv_kernel<<<dim3(H_DIM / 32, S_DIM / 32), tb, 0, stream>>>(hwf_w1, wf1T, S_DIM, H_DIM);
  tconv_kernel<<<dim3(E_DIM / 32, H_DIM / 32), tb, 0, stream>>>(hwf_w2, wf2T, H_DIM, E_DIM);
  tconv_kernel<<<dim3(E_DIM / 32, S_DIM / 32), tb, 0, stream>>>(v_w1, wv1T, S_DIM, E_DIM);

  // small/medium GEMMs
  gemm_bt<1><<<dim3(H_DIM / 128, B_SZ / 128), 256, 0, stream>>>(st_bf, w11T, hw1_b1, h1, B_SZ, H_DIM, S_DIM);
  gemm_bt<1><<<dim3(H_DIM / 128, B_SZ / 128), 256, 0, stream>>>(st_bf, wf1T, hwf_b1, hfb, B_SZ, H_DIM, S_DIM);
  gemm_bt<0><<<dim3(E_DIM / 128, B_SZ / 128), 256, 0, stream>>>(st_bf, wb1T, hb1_b, b1f, B_SZ, E_DIM, S_DIM);
  gemm_bt<1><<<dim3(E_DIM / 128, B_SZ / 128), 256, 0, stream>>>(st_bf, wv1T, v_b1, vhb, B_SZ, E_DIM, S_DIM);
  gemm_bt<2><<<dim3(E_DIM / 128, B_SZ / 128), 256, 0, stream>>>(hfb, wf2T, hwf_b2, wfb, B_SZ, E_DIM, H_DIM);

  // big GEMM (w1) in row-chunks + fused contraction/epilogue
  for (int row0 = 0; row0 < B_SZ; row0 += chunk) {
    int cm = chunk;
    if (row0 + cm > B_SZ) cm = B_SZ - row0;
    gemm_bt<2><<<dim3(8192 / 128, cm / 128), 256, 0, stream>>>(
        h1 + (size_t)row0 * H_DIM, w12T, hw1_b2, w1c, cm, 8192, H_DIM);
    final_kernel<<<cm, 256, 0, stream>>>(agent_qs, w1c, b1f, wfb, vhb, v_w2, v_b2, out, row0);
  }
}

// Round 2
// 251.611 us; speedup vs baseline: 1.1187x; 1.1187x over previous
//
#include <hip/hip_runtime.h>
#include <hip/hip_bf16.h>

#define B_SZ 8192
#define S_DIM 512
#define H_DIM 1024
#define E_DIM 256
#define A_DIM 32

typedef __attribute__((ext_vector_type(4))) float f32x4;
typedef __attribute__((ext_vector_type(8))) __bf16 bf16x8;

using as1_void = __attribute__((address_space(1))) void;
using as3_void = __attribute__((address_space(3))) void;

__device__ __forceinline__ unsigned short f2bfu(float f) {
  unsigned u = __builtin_bit_cast(unsigned, f);
  unsigned r = (u + 0x7FFFu + ((u >> 16) & 1u)) >> 16;
  return (unsigned short)r;
}
__device__ __forceinline__ float bf2f(unsigned short x) {
  unsigned u = ((unsigned)x) << 16;
  return __builtin_bit_cast(float, u);
}

// elementwise f32 -> bf16 (n multiple of 4)
__global__ void conv_kernel(const float* __restrict__ in, unsigned short* __restrict__ out, int n) {
  int i = blockIdx.x * blockDim.x + threadIdx.x;
  int idx = i * 4;
  if (idx >= n) return;
  const float4 v = *(const float4*)(in + idx);
  ushort4 o;
  o.x = f2bfu(v.x); o.y = f2bfu(v.y); o.z = f2bfu(v.z); o.w = f2bfu(v.w);
  *(ushort4*)(out + idx) = o;
}

// transpose+convert: in [R][C] f32 -> out [C][R] bf16. R,C multiples of 32.
__global__ void tconv_kernel(const float* __restrict__ in, unsigned short* __restrict__ out,
                             int R, int C) {
  __shared__ float t[32][33];
  int tx = threadIdx.x, ty = threadIdx.y;
  int c0 = blockIdx.x * 32, r0 = blockIdx.y * 32;
#pragma unroll
  for (int i = 0; i < 4; ++i) {
    int r = r0 + ty + i * 8;
    t[ty + i * 8][tx] = in[(size_t)r * C + c0 + tx];
  }
  __syncthreads();
#pragma unroll
  for (int i = 0; i < 4; ++i) {
    int c = c0 + ty + i * 8;
    out[(size_t)c * R + r0 + tx] = f2bfu(t[tx][ty + i * 8]);
  }
}

// ---------------- 128x128 2-phase GEMM (m97 structure) for small/medium GEMMs -------------
// C[M,N] = act(A[M,K] @ B[K,N] + bias), with B given transposed: BT[N][K].
template <int ACT>
__global__ void gemm_bt(const unsigned short* __restrict__ A,
                        const unsigned short* __restrict__ BT,
                        const float* __restrict__ bias, void* __restrict__ Cp,
                        int M, int N, int K) {
  __shared__ unsigned short As[128 * 64];
  __shared__ unsigned short Bs[128 * 64];
  const int tid = threadIdx.x;
  const int w = tid >> 6, l = tid & 63;
  const int wr = w >> 1, wc = w & 1;
  const int row0 = blockIdx.y * 128, col0 = blockIdx.x * 128;
  f32x4 acc[4][4] = {};
  for (int k0 = 0; k0 < K; k0 += 64) {
    __syncthreads();
#pragma unroll
    for (int i = 0; i < 4; ++i) {
      int cbase = i * 256 + w * 64;
      int c = cbase + l;
      int r = c >> 3, kc = c & 7;
      const unsigned short* src = A + (size_t)(row0 + r) * K + (k0 + kc * 8);
      __builtin_amdgcn_global_load_lds((const as1_void*)src, (as3_void*)&As[cbase * 8], 16, 0, 0);
    }
#pragma unroll
    for (int i = 0; i < 4; ++i) {
      int cbase = i * 256 + w * 64;
      int c = cbase + l;
      int r = c >> 3, kc = c & 7;
      const unsigned short* src = BT + (size_t)(col0 + r) * K + (k0 + kc * 8);
      __builtin_amdgcn_global_load_lds((const as1_void*)src, (as3_void*)&Bs[cbase * 8], 16, 0, 0);
    }
    __syncthreads();
#pragma unroll
    for (int kk = 0; kk < 2; ++kk) {
      bf16x8 af[4], bfr[4];
#pragma unroll
      for (int i = 0; i < 4; ++i)
        af[i] = *(const bf16x8*)&As[(wr * 64 + i * 16 + (l & 15)) * 64 + kk * 32 + (l >> 4) * 8];
#pragma unroll
      for (int j = 0; j < 4; ++j)
        bfr[j] = *(const bf16x8*)&Bs[(wc * 64 + j * 16 + (l & 15)) * 64 + kk * 32 + (l >> 4) * 8];
#pragma unroll
      for (int i = 0; i < 4; ++i)
#pragma unroll
        for (int j = 0; j < 4; ++j)
          acc[i][j] = __builtin_amdgcn_mfma_f32_16x16x32_bf16(af[i], bfr[j], acc[i][j], 0, 0, 0);
    }
  }
#pragma unroll
  for (int i = 0; i < 4; ++i)
#pragma unroll
    for (int j = 0; j < 4; ++j)
#pragma unroll
      for (int t = 0; t < 4; ++t) {
        int r = row0 + wr * 64 + i * 16 + (l >> 4) * 4 + t;
        int c = col0 + wc * 64 + j * 16 + (l & 15);
        float v = acc[i][j][t] + bias[c];
        if (ACT == 1) v = fmaxf(v, 0.0f);
        if (ACT == 2) v = fabsf(v);
        if (ACT == 0)
          ((float*)Cp)[(size_t)r * N + c] = v;
        else
          ((unsigned short*)Cp)[(size_t)r * N + c] = f2bfu(v);
      }
}

// ---------------- 256x256 deep-pipelined GEMM (T2+T3+T4+T5) -----------------------------
// Quadrant order per K-tile: [Ah0xBh0, Ah0xBh1, Ah1xBh0, Ah1xBh1]
// Stage order per K-tile (for tile t+1): [Ah0, Bh0, Bh1, Ah1] — one half-tile per phase.
// Counted vmcnt(4) at p0/p1/p3 ends (none at p2); last tile peeled with vmcnt(2)/vmcnt(0).
// LDS chunk swizzle: 16B chunk kc stored at kc ^ (row&7), applied on global source AND ds_read.
template <int ACT>
__global__ __launch_bounds__(512, 2) void gemm256_bt(
    const unsigned short* __restrict__ A, const unsigned short* __restrict__ BT,
    const float* __restrict__ bias, void* __restrict__ Cp, int M, int N, int K) {
  __shared__ __align__(16) char smem[131072];  // A: [0,64K) B: [64K,128K); each: 2 buf x 2 half x 16KB
  const int tid = threadIdx.x;
  const int w = tid >> 6, l = tid & 63;
  const int wrow = w >> 2, wcol = w & 3;
  const int row0 = blockIdx.y * 256, col0 = blockIdx.x * 256;
  const int NT = K >> 6;  // requires NT >= 2

  bf16x8 af[8];   // A-frags for current A-half: [i][kk]
  bf16x8 bfr[4];  // B-frags for current B-half: [j][kk]
  f32x4 acc[2][2][4][2] = {};

  auto stage = [&](int mat, int h, int t, int buf) {
    const unsigned short* base = mat ? BT : A;
    const int rbase = (mat ? col0 : row0) + h * 128;
    const int k0 = t * 64;
    char* region = smem + mat * 65536 + buf * 32768 + h * 16384;
#pragma unroll
    for (int j = 0; j < 2; ++j) {
      const int c = j * 512 + w * 64 + l;  // chunk id 0..1023
      const int r = c >> 3, kc = c & 7;
      const unsigned short* src =
          base + (size_t)(rbase + r) * K + (k0 + ((kc ^ (r & 7)) << 3));
      __builtin_amdgcn_global_load_lds((const as1_void*)src,
                                       (as3_void*)(region + (j * 512 + w * 64) * 16), 16, 0, 0);
    }
  };
  auto lda = [&](int qa, int buf) {
    const char* region = smem + buf * 32768 + qa * 16384;
#pragma unroll
    for (int i = 0; i < 4; ++i) {
      const int r = wrow * 64 + i * 16 + (l & 15);
#pragma unroll
      for (int kk = 0; kk < 2; ++kk) {
        const int kc = kk * 4 + (l >> 4);
        af[i * 2 + kk] = *(const bf16x8*)(region + r * 128 + ((kc ^ (r & 7)) << 4));
      }
    }
  };
  auto ldb = [&](int qb, int buf) {
    const char* region = smem + 65536 + buf * 32768 + qb * 16384;
#pragma unroll
    for (int j = 0; j < 2; ++j) {
      const int r = wcol * 32 + j * 16 + (l & 15);
#pragma unroll
      for (int kk = 0; kk < 2; ++kk) {
        const int kc = kk * 4 + (l >> 4);
        bfr[j * 2 + kk] = *(const bf16x8*)(region + r * 128 + ((kc ^ (r & 7)) << 4));
      }
    }
  };
  auto mf = [&](f32x4 (&ac)[4][2]) {
    __builtin_amdgcn_s_setprio(1);
#pragma unroll
    for (int i = 0; i < 4; ++i)
#pragma unroll
      for (int j = 0; j < 2; ++j)
#pragma unroll
        for (int kk = 0; kk < 2; ++kk)
          ac[i][j] = __builtin_amdgcn_mfma_f32_16x16x32_bf16(af[i * 2 + kk], bfr[j * 2 + kk],
                                                             ac[i][j], 0, 0, 0);
    __builtin_amdgcn_s_setprio(0);
  };
  auto bar = [&]() {
    asm volatile("" ::: "memory");
    __builtin_amdgcn_s_barrier();
    asm volatile("" ::: "memory");
  };

  // prologue: tile 0, stage order [Ah0, Bh0, Bh1, Ah1]
  stage(0, 0, 0, 0); stage(1, 0, 0, 0); stage(1, 1, 0, 0); stage(0, 1, 0, 0);
  asm volatile("s_waitcnt vmcnt(4)" ::: "memory");
  bar();

  for (int t = 0; t < NT - 1; ++t) {
    const int buf = t & 1, nbuf = buf ^ 1;
    // p0: q(Ah0,Bh0); stage t+1.Ah0
    lda(0, buf); ldb(0, buf);
    stage(0, 0, t + 1, nbuf);
    asm volatile("s_waitcnt vmcnt(4)" ::: "memory");
    bar();
    mf(acc[0][0]);
    // p1: q(Ah0,Bh1); stage t+1.Bh0
    ldb(1, buf);
    stage(1, 0, t + 1, nbuf);
    asm volatile("s_waitcnt vmcnt(4)" ::: "memory");
    bar();
    mf(acc[0][1]);
    // p2: q(Ah1,Bh0); stage t+1.Bh1 — no vmcnt (q3 needs nothing new)
    lda(1, buf); ldb(0, buf);
    stage(1, 1, t + 1, nbuf);
    bar();
    mf(acc[1][0]);
    // p3: q(Ah1,Bh1); stage t+1.Ah1
    ldb(1, buf);
    stage(0, 1, t + 1, nbuf);
    asm volatile("s_waitcnt vmcnt(4)" ::: "memory");
    bar();
    mf(acc[1][1]);
  }
  {  // last tile, no staging; tight waits for the 2 half-tiles still in flight
    const int buf = (NT - 1) & 1;
    lda(0, buf); ldb(0, buf);
    asm volatile("s_waitcnt vmcnt(2)" ::: "memory");
    bar();
    mf(acc[0][0]);
    ldb(1, buf);
    asm volatile("s_waitcnt vmcnt(0)" ::: "memory");
    bar();
    mf(acc[0][1]);
    lda(1, buf); ldb(0, buf);
    bar();
    mf(acc[1][0]);
    ldb(1, buf);
    bar();
    mf(acc[1][1]);
  }

#pragma unroll
  for (int qa = 0; qa < 2; ++qa)
#pragma unroll
    for (int qb = 0; qb < 2; ++qb)
#pragma unroll
      for (int i = 0; i < 4; ++i)
#pragma unroll
        for (int j = 0; j < 2; ++j)
#pragma unroll
          for (int tt = 0; tt < 4; ++tt) {
            const int r = row0 + qa * 128 + wrow * 64 + i * 16 + (l >> 4) * 4 + tt;
            const int cc = col0 + qb * 128 + wcol * 32 + j * 16 + (l & 15);
            float v = acc[qa][qb][i][j][tt] + bias[cc];
            if (ACT == 1) v = fmaxf(v, 0.0f);
            if (ACT == 2) v = fabsf(v);
            if (ACT == 0)
              ((float*)Cp)[(size_t)r * N + cc] = v;
            else
              ((unsigned short*)Cp)[(size_t)r * N + cc] = f2bfu(v);
          }
}

// Per-row fusion: hidden = elu(sum_a q[a]*|w1[b,a,:]| + b1), q_tot = hidden.wf + vh.vw2 + vb2
__global__ void final_kernel(const float* __restrict__ qs, const unsigned short* __restrict__ w1c,
                             const float* __restrict__ b1, const unsigned short* __restrict__ wf,
                             const unsigned short* __restrict__ vh, const float* __restrict__ vw2,
                             const float* __restrict__ vb2, float* __restrict__ out, int row0) {
  const int tid = threadIdx.x;               // e in [0,256)
  const int b = row0 + blockIdx.x;
  const unsigned short* wrow = w1c + (size_t)blockIdx.x * (A_DIM * E_DIM);
  const float* qrow = qs + (size_t)b * A_DIM;
  float acc = b1[(size_t)b * E_DIM + tid];
#pragma unroll 8
  for (int a = 0; a < A_DIM; ++a)
    acc = fmaf(qrow[a], bf2f(wrow[a * E_DIM + tid]), acc);
  float hidden = acc > 0.0f ? acc : (expf(acc) - 1.0f);  // elu, alpha=1
  float s = hidden * bf2f(wf[(size_t)b * E_DIM + tid]) +
            bf2f(vh[(size_t)b * E_DIM + tid]) * vw2[tid];
  __shared__ float red[4];
#pragma unroll
  for (int o = 32; o > 0; o >>= 1) s += __shfl_down(s, o, 64);
  if ((tid & 63) == 0) red[tid >> 6] = s;
  __syncthreads();
  if (tid == 0) out[b] = red[0] + red[1] + red[2] + red[3] + vb2[0];
}

extern "C" void kernel_launch(void* const* d_in, const int* in_sizes, int n_in,
                              void* d_out, int out_size, void* d_ws, size_t ws_size,
                              hipStream_t stream) {
  const float* agent_qs = (const float*)d_in[0];
  const float* states = (const float*)d_in[1];
  const float* hw1_w1 = (const float*)d_in[2];
  const float* hw1_b1 = (const float*)d_in[3];
  const float* hw1_w2 = (const float*)d_in[4];
  const float* hw1_b2 = (const float*)d_in[5];
  const float* hb1_w = (const float*)d_in[6];
  const float* hb1_b = (const float*)d_in[7];
  const float* hwf_w1 = (const float*)d_in[8];
  const float* hwf_b1 = (const float*)d_in[9];
  const float* hwf_w2 = (const float*)d_in[10];
  const float* hwf_b2 = (const float*)d_in[11];
  const float* v_w1 = (const float*)d_in[12];
  const float* v_b1 = (const float*)d_in[13];
  const float* v_w2 = (const float*)d_in[14];
  const float* v_b2 = (const float*)d_in[15];
  float* out = (float*)d_out;

  size_t off = 0;
  char* ws = (char*)d_ws;
  auto carve = [&](size_t bytes) -> void* {
    void* p = ws + off;
    off = (off + bytes + 255) & ~(size_t)255;
    return p;
  };
  unsigned short* st_bf = (unsigned short*)carve((size_t)B_SZ * S_DIM * 2);
  unsigned short* w11T = (unsigned short*)carve((size_t)H_DIM * S_DIM * 2);
  unsigned short* w12T = (unsigned short*)carve((size_t)8192 * H_DIM * 2);
  unsigned short* wb1T = (unsigned short*)carve((size_t)E_DIM * S_DIM * 2);
  unsigned short* wf1T = (unsigned short*)carve((size_t)H_DIM * S_DIM * 2);
  unsigned short* wf2T = (unsigned short*)carve((size_t)E_DIM * H_DIM * 2);
  unsigned short* wv1T = (unsigned short*)carve((size_t)E_DIM * S_DIM * 2);
  unsigned short* h1 = (unsigned short*)carve((size_t)B_SZ * H_DIM * 2);
  unsigned short* hfb = (unsigned short*)carve((size_t)B_SZ * H_DIM * 2);
  float* b1f = (float*)carve((size_t)B_SZ * E_DIM * 4);
  unsigned short* wfb = (unsigned short*)carve((size_t)B_SZ * E_DIM * 2);
  unsigned short* vhb = (unsigned short*)carve((size_t)B_SZ * E_DIM * 2);
  size_t rem = (ws_size > off) ? ws_size - off : 0;
  int chunk = (int)(rem / ((size_t)8192 * 2));
  chunk &= ~255;
  if (chunk < 256) chunk = 256;
  if (chunk > B_SZ) chunk = B_SZ;
  unsigned short* w1c = (unsigned short*)(ws + off);

  // dtype converts (+ weight transposes to B^T layout)
  conv_kernel<<<(B_SZ * S_DIM / 4 + 255) / 256, 256, 0, stream>>>(states, st_bf, B_SZ * S_DIM);
  dim3 tb(32, 8);
  tconv_kernel<<<dim3(H_DIM / 32, S_DIM / 32), tb, 0, stream>>>(hw1_w1, w11T, S_DIM, H_DIM);
  tconv_kernel<<<dim3(8192 / 32, H_DIM / 32), tb, 0, stream>>>(hw1_w2, w12T, H_DIM, 8192);
  tconv_kernel<<<dim3(E_DIM / 32, S_DIM / 32), tb, 0, stream>>>(hb1_w, wb1T, S_DIM, E_DIM);
  tconv_kernel<<<dim3(H_DIM / 32, S_DIM / 32), tb, 0, stream>>>(hwf_w1, wf1T, S_DIM, H_DIM);
  tconv_kernel<<<dim3(E_DIM / 32, H_DIM / 32), tb, 0, stream>>>(hwf_w2, wf2T, H_DIM, E_DIM);
  tconv_kernel<<<dim3(E_DIM / 32, S_DIM / 32), tb, 0, stream>>>(v_w1, wv1T, S_DIM, E_DIM);

  // small/medium GEMMs (128-tile 2-phase structure)
  gemm_bt<1><<<dim3(H_DIM / 128, B_SZ / 128), 256, 0, stream>>>(st_bf, w11T, hw1_b1, h1, B_SZ, H_DIM, S_DIM);
  gemm_bt<1><<<dim3(H_DIM / 128, B_SZ / 128), 256, 0, stream>>>(st_bf, wf1T, hwf_b1, hfb, B_SZ, H_DIM, S_DIM);
  gemm_bt<0><<<dim3(E_DIM / 128, B_SZ / 128), 256, 0, stream>>>(st_bf, wb1T, hb1_b, b1f, B_SZ, E_DIM, S_DIM);
  gemm_bt<1><<<dim3(E_DIM / 128, B_SZ / 128), 256, 0, stream>>>(st_bf, wv1T, v_b1, vhb, B_SZ, E_DIM, S_DIM);
  gemm_bt<2><<<dim3(E_DIM / 128, B_SZ / 128), 256, 0, stream>>>(hfb, wf2T, hwf_b2, wfb, B_SZ, E_DIM, H_DIM);

  // big GEMM (w1) on the 256-tile deep pipeline, in row-chunks + fused epilogue
  for (int row0 = 0; row0 < B_SZ; row0 += chunk) {
    int cm = chunk;
    if (row0 + cm > B_SZ) cm = B_SZ - row0;
    gemm256_bt<2><<<dim3(8192 / 256, cm / 256), 512, 0, stream>>>(
        h1 + (size_t)row0 * H_DIM, w12T, hw1_b2, w1c, cm, 8192, H_DIM);
    final_kernel<<<cm, 256, 0, stream>>>(agent_qs, w1c, b1f, wfb, vhb, v_w2, v_b2, out, row0);
  }
}